// Round 8
// baseline (923.570 us; speedup 1.0000x reference)
//
#include <hip/hip_runtime.h>

#define NTOK 32768

// ---------------- conv 3x3 SAME + bias -> z[token][32] ----------------
__global__ __launch_bounds__(256) void conv_kernel(
    const float* __restrict__ x, const float* __restrict__ w,
    const float* __restrict__ bias, float* __restrict__ z) {
  __shared__ float xs[16 * 32];     // [ci][y*8+x]
  __shared__ float wsm[32 * 145];   // [co][ci*9+t], padded stride 145
  __shared__ float bs[32];
  int b = blockIdx.x, tid = threadIdx.x;
  const float* xb = x + b * 512;
  for (int i = tid; i < 512; i += 256) xs[i] = xb[i];
  for (int i = tid; i < 4608; i += 256) wsm[(i / 144) * 145 + (i % 144)] = w[i];
  if (tid < 32) bs[tid] = bias[tid];
  __syncthreads();
  #pragma unroll
  for (int r = 0; r < 4; ++r) {
    int oid = r * 256 + tid;
    int co = oid & 31, pos = oid >> 5;
    int y = pos >> 3, xx = pos & 7;
    float acc = bs[co];
    const float* wr = &wsm[co * 145];
    for (int ci = 0; ci < 16; ++ci) {
      #pragma unroll
      for (int ky = 0; ky < 3; ++ky) {
        int yy = y + ky - 1;
        if (yy < 0 || yy > 3) continue;
        #pragma unroll
        for (int kx = 0; kx < 3; ++kx) {
          int xc = xx + kx - 1;
          if (xc < 0 || xc > 7) continue;
          acc += xs[ci * 32 + yy * 8 + xc] * wr[ci * 9 + ky * 3 + kx];
        }
      }
    }
    z[(b * 32 + pos) * 32 + co] = acc;
  }
}

// ---------------- qkv projection -> transposed slabs [pos*4+h][b][8] ----------------
__global__ __launch_bounds__(256) void qkv_kernel(
    const float* __restrict__ z, const float* __restrict__ W,
    const float* __restrict__ bias, float* __restrict__ qt,
    float* __restrict__ kt, float* __restrict__ vt) {
  __shared__ float wsm[96 * 32];
  __shared__ float bs[96];
  int tid = threadIdx.x;
  for (int i = tid; i < 3072; i += 256) wsm[i] = W[i];
  if (tid < 96) bs[tid] = bias[tid];
  __syncthreads();
  int s = tid >> 3, bl = tid & 7;
  int b = blockIdx.x * 8 + bl;
  int token = b * 32 + s;
  float zr[32];
  const float4* zp = (const float4*)(z + token * 32);
  #pragma unroll
  for (int i = 0; i < 8; ++i) {
    float4 v = zp[i];
    zr[i * 4 + 0] = v.x; zr[i * 4 + 1] = v.y; zr[i * 4 + 2] = v.z; zr[i * 4 + 3] = v.w;
  }
  for (int part = 0; part < 3; ++part) {
    float* dst = part == 0 ? qt : (part == 1 ? kt : vt);
    for (int hh = 0; hh < 4; ++hh) {
      float out[8];
      #pragma unroll
      for (int j = 0; j < 8; ++j) {
        int jj = part * 32 + hh * 8 + j;
        float a = bs[jj];
        const float* wr = &wsm[jj * 32];
        #pragma unroll
        for (int k = 0; k < 32; ++k) a += zr[k] * wr[k];
        out[j] = a;
      }
      float4* p = (float4*)(dst + ((size_t)(s * 4 + hh) * 1024 + b) * 8);
      p[0] = make_float4(out[0], out[1], out[2], out[3]);
      p[1] = make_float4(out[4], out[5], out[6], out[7]);
    }
  }
}

// ---------------- attention (one-pass, no-max softmax): block per (slab, qchunk) ----------------
// exp(s)/sum(exp(s)) == exp(s-m)/sum(exp(s-m)) exactly; |s| << 80 here so no overflow.
__global__ __launch_bounds__(256) void attn_kernel(
    const float* __restrict__ qt, const float* __restrict__ kt,
    const float* __restrict__ vt, float* __restrict__ o) {
  __shared__ __align__(16) float Ks[1024 * 8];
  __shared__ __align__(16) float Vs[1024 * 8];
  int slab = blockIdx.x >> 2, qc = blockIdx.x & 3;
  int tid = threadIdx.x;
  const float4* kp = (const float4*)(kt + (size_t)slab * 8192);
  const float4* vp = (const float4*)(vt + (size_t)slab * 8192);
  float4* ksp = (float4*)Ks;
  float4* vsp = (float4*)Vs;
  for (int i = tid; i < 2048; i += 256) { ksp[i] = kp[i]; vsp[i] = vp[i]; }
  __syncthreads();
  int b = qc * 256 + tid;
  const float4* qp = (const float4*)(qt + ((size_t)slab * 1024 + b) * 8);
  float4 q0 = qp[0], q1 = qp[1];
  const float scale = 0.35355339059327373f;
  q0.x *= scale; q0.y *= scale; q0.z *= scale; q0.w *= scale;
  q1.x *= scale; q1.y *= scale; q1.z *= scale; q1.w *= scale;
  float l = 0.f;
  float a0 = 0, a1 = 0, a2 = 0, a3 = 0, a4 = 0, a5 = 0, a6 = 0, a7 = 0;
  #pragma unroll 4
  for (int t = 0; t < 1024; ++t) {
    const float4* kk = (const float4*)&Ks[t * 8];
    float4 k0 = kk[0], k1 = kk[1];
    float s = q0.x * k0.x + q0.y * k0.y + q0.z * k0.z + q0.w * k0.w +
              q1.x * k1.x + q1.y * k1.y + q1.z * k1.z + q1.w * k1.w;
    float p = __expf(s);
    l += p;
    const float4* vv = (const float4*)&Vs[t * 8];
    float4 v0 = vv[0], v1 = vv[1];
    a0 += p * v0.x; a1 += p * v0.y; a2 += p * v0.z; a3 += p * v0.w;
    a4 += p * v1.x; a5 += p * v1.y; a6 += p * v1.z; a7 += p * v1.w;
  }
  float inv = 1.f / l;
  int npos = slab >> 2, hh = slab & 3;
  float4* op = (float4*)(o + ((size_t)(b * 32 + npos)) * 32 + hh * 8);
  op[0] = make_float4(a0 * inv, a1 * inv, a2 * inv, a3 * inv);
  op[1] = make_float4(a4 * inv, a5 * inv, a6 * inv, a7 * inv);
}

// ---------------- out-proj + residual + LN1 ----------------
__global__ __launch_bounds__(256) void proj_ln1_kernel(
    const float* __restrict__ z, const float* __restrict__ o,
    const float* __restrict__ W, const float* __restrict__ bias,
    const float* __restrict__ lw, const float* __restrict__ lb,
    float* __restrict__ zn1) {
  __shared__ float wsm[1024];
  __shared__ float bs[32], lws[32], lbs[32];
  int tid = threadIdx.x;
  for (int i = tid; i < 1024; i += 256) wsm[i] = W[i];
  if (tid < 32) { bs[tid] = bias[tid]; lws[tid] = lw[tid]; lbs[tid] = lb[tid]; }
  __syncthreads();
  int token = blockIdx.x * 256 + tid;
  float orow[32], zrow[32], v[32];
  const float4* opnt = (const float4*)(o + (size_t)token * 32);
  const float4* zp = (const float4*)(z + (size_t)token * 32);
  #pragma unroll
  for (int i = 0; i < 8; ++i) {
    float4 t4 = opnt[i];
    orow[i * 4] = t4.x; orow[i * 4 + 1] = t4.y; orow[i * 4 + 2] = t4.z; orow[i * 4 + 3] = t4.w;
    float4 z4 = zp[i];
    zrow[i * 4] = z4.x; zrow[i * 4 + 1] = z4.y; zrow[i * 4 + 2] = z4.z; zrow[i * 4 + 3] = z4.w;
  }
  float s1 = 0.f, s2 = 0.f;
  for (int j = 0; j < 32; ++j) {
    float a = bs[j];
    const float* wr = &wsm[j * 32];
    #pragma unroll
    for (int k = 0; k < 32; ++k) a += orow[k] * wr[k];
    float t = a + zrow[j];
    v[j] = t; s1 += t; s2 += t * t;
  }
  float mean = s1 * (1.f / 32.f);
  float var = s2 * (1.f / 32.f) - mean * mean;
  float rs = rsqrtf(var + 1e-5f);
  float4* dst = (float4*)(zn1 + (size_t)token * 32);
  #pragma unroll
  for (int k4 = 0; k4 < 8; ++k4) {
    float4 ov;
    ov.x = (v[k4 * 4 + 0] - mean) * rs * lws[k4 * 4 + 0] + lbs[k4 * 4 + 0];
    ov.y = (v[k4 * 4 + 1] - mean) * rs * lws[k4 * 4 + 1] + lbs[k4 * 4 + 1];
    ov.z = (v[k4 * 4 + 2] - mean) * rs * lws[k4 * 4 + 2] + lbs[k4 * 4 + 2];
    ov.w = (v[k4 * 4 + 3] - mean) * rs * lws[k4 * 4 + 3] + lbs[k4 * 4 + 3];
    dst[k4] = ov;
  }
}

// ---------------- w2 pre-transpose: w2t[f][d] = w2[d][f] ----------------
__global__ __launch_bounds__(256) void w2t_kernel(
    const float* __restrict__ w2, float* __restrict__ w2t) {
  __shared__ float ts[32 * 33];
  int f0 = blockIdx.x * 32;
  int tid = threadIdx.x;
  int a = tid & 31, bq = tid >> 5;
  #pragma unroll
  for (int r = 0; r < 4; ++r) {
    int d = bq + r * 8;
    ts[a * 33 + d] = w2[(size_t)d * 2048 + f0 + a];   // lanes a fast: coalesced
  }
  __syncthreads();
  #pragma unroll
  for (int r = 0; r < 4; ++r) {
    int fi = bq + r * 8;
    w2t[(size_t)(f0 + fi) * 32 + a] = ts[fi * 33 + a]; // lanes a fast: coalesced
  }
}

// ---------------- fused FFN v5: 4 tok/thread register-blocked, 8-lane f-split ----------------
// LDS-pipe bound analysis (R6): 256 ds_read_b128/thread/chunk is fixed cost;
// T=4 tokens amortizes it over 4096 FMAs (halves per-token LDS time vs T=2).
// VGPR ~300 needed -> __launch_bounds__(256,1); 256 blocks = 1/CU, 1 wave/SIMD.
// Staging + compute-read bank patterns identical to R6 (measured 0 conflicts).
__global__ __launch_bounds__(256, 1) void ffn_kernel(
    const float* __restrict__ zn1, const float* __restrict__ w1,
    const float* __restrict__ b1, const float* __restrict__ w2t,
    const float* __restrict__ b2, const float* __restrict__ lw,
    const float* __restrict__ lb, float* __restrict__ zn2) {
  __shared__ __align__(16) float w1s[128 * 36];
  __shared__ __align__(16) float w2s[128 * 36];
  __shared__ float b1s[128];
  __shared__ float lws[32], lbs[32], b2s[32];
  int tid = threadIdx.x;
  int p = tid >> 3, fg = tid & 7;
  int t0 = blockIdx.x * 128 + p * 4;
  float z[4][32], acc[4][32];
  #pragma unroll
  for (int j = 0; j < 4; ++j) {
    const float4* zp = (const float4*)(zn1 + (size_t)(t0 + j) * 32);
    #pragma unroll
    for (int i = 0; i < 8; ++i) {
      float4 a = zp[i];
      z[j][i * 4 + 0] = a.x; z[j][i * 4 + 1] = a.y;
      z[j][i * 4 + 2] = a.z; z[j][i * 4 + 3] = a.w;
    }
    #pragma unroll
    for (int d = 0; d < 32; ++d) acc[j][d] = 0.f;
  }
  if (tid < 32) { lws[tid] = lw[tid]; lbs[tid] = lb[tid]; b2s[tid] = b2[tid]; }
  for (int ch = 0; ch < 16; ++ch) {
    __syncthreads();
    #pragma unroll
    for (int pass = 0; pass < 16; ++pass) {
      int idx = pass * 256 + tid;        // 0..4095
      int f = idx >> 5, k = idx & 31;
      w1s[f * 36 + k] = w1[(size_t)(ch * 128 + f) * 32 + k];
      w2s[f * 36 + k] = w2t[(size_t)(ch * 128 + f) * 32 + k];
    }
    if (tid < 128) b1s[tid] = b1[ch * 128 + tid];
    __syncthreads();
    #pragma unroll 2
    for (int i = 0; i < 16; ++i) {
      int f = i * 8 + fg;
      const float4* wr = (const float4*)&w1s[f * 36];
      float h[4];
      float bb = b1s[f];
      h[0] = bb; h[1] = bb; h[2] = bb; h[3] = bb;
      #pragma unroll
      for (int k4 = 0; k4 < 8; ++k4) {
        float4 wv = wr[k4];
        #pragma unroll
        for (int j = 0; j < 4; ++j) {
          h[j] += z[j][k4 * 4 + 0] * wv.x + z[j][k4 * 4 + 1] * wv.y +
                  z[j][k4 * 4 + 2] * wv.z + z[j][k4 * 4 + 3] * wv.w;
        }
      }
      #pragma unroll
      for (int j = 0; j < 4; ++j) h[j] = fmaxf(h[j], 0.f);
      const float4* vr = (const float4*)&w2s[f * 36];
      #pragma unroll
      for (int d4 = 0; d4 < 8; ++d4) {
        float4 vv = vr[d4];
        #pragma unroll
        for (int j = 0; j < 4; ++j) {
          acc[j][d4 * 4 + 0] += h[j] * vv.x; acc[j][d4 * 4 + 1] += h[j] * vv.y;
          acc[j][d4 * 4 + 2] += h[j] * vv.z; acc[j][d4 * 4 + 3] += h[j] * vv.w;
        }
      }
    }
  }
  // reduce across the 8 fg lanes (adjacent in-wave)
  #pragma unroll
  for (int j = 0; j < 4; ++j) {
    #pragma unroll
    for (int d = 0; d < 32; ++d) {
      float a = acc[j][d];
      a += __shfl_xor(a, 1); a += __shfl_xor(a, 2); a += __shfl_xor(a, 4);
      acc[j][d] = a;
    }
  }
  if (fg == 0) {
    #pragma unroll
    for (int j = 0; j < 4; ++j) {
      float v[32];
      float s1 = 0.f, s2 = 0.f;
      #pragma unroll
      for (int d = 0; d < 32; ++d) {
        float t = z[j][d] + acc[j][d] + b2s[d];
        v[d] = t; s1 += t; s2 += t * t;
      }
      float mean = s1 * (1.f / 32.f);
      float var = s2 * (1.f / 32.f) - mean * mean;
      float rs = rsqrtf(var + 1e-5f);
      float4* dst = (float4*)(zn2 + (size_t)(t0 + j) * 32);
      #pragma unroll
      for (int k4 = 0; k4 < 8; ++k4) {
        float4 ov;
        ov.x = (v[k4 * 4 + 0] - mean) * rs * lws[k4 * 4 + 0] + lbs[k4 * 4 + 0];
        ov.y = (v[k4 * 4 + 1] - mean) * rs * lws[k4 * 4 + 1] + lbs[k4 * 4 + 1];
        ov.z = (v[k4 * 4 + 2] - mean) * rs * lws[k4 * 4 + 2] + lbs[k4 * 4 + 2];
        ov.w = (v[k4 * 4 + 3] - mean) * rs * lws[k4 * 4 + 3] + lbs[k4 * 4 + 3];
        dst[k4] = ov;
      }
    }
  }
}

// ---------------- transpose per batch: g[b*32+c][s] = z2[b*32+s][c] ----------------
__global__ __launch_bounds__(256) void transpose_kernel(
    const float* __restrict__ zn2, float* __restrict__ g) {
  __shared__ float t[32 * 33];
  int b = blockIdx.x, tid = threadIdx.x;
  const float* src = zn2 + (size_t)b * 1024;
  #pragma unroll
  for (int l = 0; l < 4; ++l) {
    int o_ = l * 256 + tid;
    t[(o_ >> 5) * 33 + (o_ & 31)] = src[o_];
  }
  __syncthreads();
  float* dst = g + (size_t)b * 1024;
  #pragma unroll
  for (int l = 0; l < 4; ++l) {
    int o_ = l * 256 + tid;
    int c = o_ >> 5, s = o_ & 31;
    dst[o_] = t[s * 33 + c];
  }
}

// ---------------- CSR build: int degree histogram ----------------
__global__ void degi_kernel(const int* __restrict__ col, int* __restrict__ degi, int E) {
  int e = blockIdx.x * 256 + threadIdx.x;
  if (e < E) atomicAdd(&degi[col[e]], 1);
}

// ---------------- single-block scan: offs = exclusive prefix(degi); cur=offs; dis ----------------
__global__ __launch_bounds__(1024) void scan_kernel(
    const int* __restrict__ degi, int* __restrict__ offs, int* __restrict__ cur,
    float* __restrict__ dis, int E) {
  __shared__ int ts[1024];
  int tid = threadIdx.x;
  int base = tid * 32;
  int loc[32];
  int s = 0;
  #pragma unroll
  for (int i = 0; i < 32; ++i) { loc[i] = s; s += degi[base + i]; }
  ts[tid] = s;
  __syncthreads();
  for (int d = 1; d < 1024; d <<= 1) {
    int v = (tid >= d) ? ts[tid - d] : 0;
    __syncthreads();
    ts[tid] += v;
    __syncthreads();
  }
  int excl = (tid == 0) ? 0 : ts[tid - 1];
  #pragma unroll
  for (int i = 0; i < 32; ++i) {
    int o = excl + loc[i];
    offs[base + i] = o;
    cur[base + i] = o;
    dis[base + i] = rsqrtf((float)(degi[base + i] + 1));  // +1 self-loop
  }
  if (tid == 1023) offs[NTOK] = E;
}

// ---------------- CSR fill: erec[slot] = (row, dis[row]*dis[col]) ----------------
__global__ void fill_kernel(const int* __restrict__ row, const int* __restrict__ col,
                            const float* __restrict__ dis, int* __restrict__ cur,
                            int2* __restrict__ erec, int E) {
  int e = blockIdx.x * 256 + threadIdx.x;
  if (e >= E) return;
  int r = row[e], c = col[e];
  int slot = atomicAdd(&cur[c], 1);
  float nrm = dis[r] * dis[c];
  erec[slot] = make_int2(r, __float_as_int(nrm));
}

// ---------------- GCN xw = g@W^T (layer input transform) ----------------
__global__ __launch_bounds__(256) void gcn_in_kernel(
    const float* __restrict__ g, const float* __restrict__ w,
    float* __restrict__ xw) {
  __shared__ float wsm[1024];
  int tid = threadIdx.x;
  for (int i = tid; i < 1024; i += 256) wsm[i] = w[i];
  __syncthreads();
  int n = blockIdx.x * 256 + tid;
  float gr[32];
  const float4* gp = (const float4*)(g + (size_t)n * 32);
  #pragma unroll
  for (int i = 0; i < 8; ++i) {
    float4 v = gp[i];
    gr[i * 4] = v.x; gr[i * 4 + 1] = v.y; gr[i * 4 + 2] = v.z; gr[i * 4 + 3] = v.w;
  }
  float4* xp = (float4*)(xw + (size_t)n * 32);
  for (int d4 = 0; d4 < 8; ++d4) {
    float o_[4];
    #pragma unroll
    for (int j = 0; j < 4; ++j) {
      const float* wr = &wsm[(d4 * 4 + j) * 32];
      float a = 0.f;
      #pragma unroll
      for (int k = 0; k < 32; ++k) a += gr[k] * wr[k];
      o_[j] = a;
    }
    xp[d4] = make_float4(o_[0], o_[1], o_[2], o_[3]);
  }
}

// ---------------- GCN gather: agg[c] = xw[c]*dis[c]^2 + sum_e xw[row_e]*nrm_e ----------------
__global__ __launch_bounds__(256) void gather_kernel(
    const float* __restrict__ xw, const float* __restrict__ dis,
    const int* __restrict__ offs, const int2* __restrict__ erec,
    float* __restrict__ agg) {
  int gid = blockIdx.x * 256 + threadIdx.x;
  int c = gid >> 3, q = gid & 7;
  int start = offs[c], end = offs[c + 1];
  float dn = dis[c];
  float dn2 = dn * dn;
  float4 self = ((const float4*)(xw + (size_t)c * 32))[q];
  float a0 = self.x * dn2, a1 = self.y * dn2, a2 = self.z * dn2, a3 = self.w * dn2;
  int e = start;
  #pragma unroll 4
  for (; e < end; ++e) {
    int2 rec = erec[e];
    float nrm = __int_as_float(rec.y);
    float4 v = ((const float4*)(xw + (size_t)rec.x * 32))[q];
    a0 += v.x * nrm; a1 += v.y * nrm; a2 += v.z * nrm; a3 += v.w * nrm;
  }
  ((float4*)(agg + (size_t)c * 32))[q] = make_float4(a0, a1, a2, a3);
}

// ---------------- GCN mid: g1 = relu(agg+b); xw2 = g1@W^T ----------------
__global__ __launch_bounds__(256) void gcn_mid_kernel(
    const float* __restrict__ agg, const float* __restrict__ gb,
    const float* __restrict__ w, float* __restrict__ xw2) {
  __shared__ float wsm[1024];
  __shared__ float bs[32];
  int tid = threadIdx.x;
  for (int i = tid; i < 1024; i += 256) wsm[i] = w[i];
  if (tid < 32) bs[tid] = gb[tid];
  __syncthreads();
  int n = blockIdx.x * 256 + tid;
  float gr[32];
  const float4* ap = (const float4*)(agg + (size_t)n * 32);
  #pragma unroll
  for (int i = 0; i < 8; ++i) {
    float4 v = ap[i];
    gr[i * 4 + 0] = fmaxf(v.x + bs[i * 4 + 0], 0.f);
    gr[i * 4 + 1] = fmaxf(v.y + bs[i * 4 + 1], 0.f);
    gr[i * 4 + 2] = fmaxf(v.z + bs[i * 4 + 2], 0.f);
    gr[i * 4 + 3] = fmaxf(v.w + bs[i * 4 + 3], 0.f);
  }
  float4* xp = (float4*)(xw2 + (size_t)n * 32);
  for (int d4 = 0; d4 < 8; ++d4) {
    float o_[4];
    #pragma unroll
    for (int j = 0; j < 4; ++j) {
      const float* wr = &wsm[(d4 * 4 + j) * 32];
      float a = 0.f;
      #pragma unroll
      for (int k = 0; k < 32; ++k) a += gr[k] * wr[k];
      o_[j] = a;
    }
    xp[d4] = make_float4(o_[0], o_[1], o_[2], o_[3]);
  }
}

// ---------------- final: fc + log_softmax ----------------
__global__ __launch_bounds__(256) void gcn_out_kernel(
    const float* __restrict__ agg2, const float* __restrict__ gb,
    const float* __restrict__ fw, const float* __restrict__ fb,
    float* __restrict__ out) {
  __shared__ float wsm[320];
  __shared__ float bs[10];
  __shared__ float gbs[32];
  int tid = threadIdx.x;
  for (int i = tid; i < 320; i += 256) wsm[i] = fw[i];
  if (tid < 10) bs[tid] = fb[tid];
  if (tid < 32) gbs[tid] = gb[tid];
  __syncthreads();
  int n = blockIdx.x * 256 + tid;
  float v[32];
  const float4* ap = (const float4*)(agg2 + (size_t)n * 32);
  #pragma unroll
  for (int i = 0; i < 8; ++i) {
    float4 t4 = ap[i];
    v[i * 4 + 0] = t4.x + gbs[i * 4 + 0];
    v[i * 4 + 1] = t4.y + gbs[i * 4 + 1];
    v[i * 4 + 2] = t4.z + gbs[i * 4 + 2];
    v[i * 4 + 3] = t4.w + gbs[i * 4 + 3];
  }
  float lg[10];
  float mx = -1e30f;
  for (int j = 0; j < 10; ++j) {
    float a = bs[j];
    const float* wr = &wsm[j * 32];
    #pragma unroll
    for (int k = 0; k < 32; ++k) a += v[k] * wr[k];
    lg[j] = a;
    mx = fmaxf(mx, a);
  }
  float se = 0.f;
  for (int j = 0; j < 10; ++j) se += __expf(lg[j] - mx);
  float ls = logf(se);
  for (int j = 0; j < 10; ++j) out[(size_t)n * 10 + j] = lg[j] - mx - ls;
}

extern "C" void kernel_launch(void* const* d_in, const int* in_sizes, int n_in,
                              void* d_out, int out_size, void* d_ws, size_t ws_size,
                              hipStream_t stream) {
  const float* x      = (const float*)d_in[0];
  const int*   ei     = (const int*)d_in[1];
  const float* conv_w = (const float*)d_in[2];
  const float* conv_b = (const float*)d_in[3];
  const float* in_w   = (const float*)d_in[4];
  const float* in_b   = (const float*)d_in[5];
  const float* out_w  = (const float*)d_in[6];
  const float* out_b  = (const float*)d_in[7];
  const float* ln1_w  = (const float*)d_in[8];
  const float* ln1_b  = (const float*)d_in[9];
  const float* ln2_w  = (const float*)d_in[10];
  const float* ln2_b  = (const float*)d_in[11];
  const float* ff1_w  = (const float*)d_in[12];
  const float* ff1_b  = (const float*)d_in[13];
  const float* ff2_w  = (const float*)d_in[14];
  const float* ff2_b  = (const float*)d_in[15];
  const float* gcn_w  = (const float*)d_in[16];
  const float* gcn_b  = (const float*)d_in[17];
  const float* fc_w   = (const float*)d_in[18];
  const float* fc_b   = (const float*)d_in[19];
  int E = in_sizes[1] / 2;
  const int* rowp = ei;
  const int* colp = ei + E;

  float* wsf = (float*)d_ws;
  const size_t M = 1048576;  // floats per 4 MB buffer
  float* Z   = wsf + 0 * M;
  float* QT  = wsf + 1 * M;
  float* KT  = wsf + 2 * M;
  float* VT  = wsf + 3 * M;
  float* O   = wsf + 4 * M;
  float* ZN1 = wsf + 5 * M;
  float* ZN2 = wsf + 6 * M;
  // CSR area after the 7 big buffers
  int*   DEGI = (int*)(wsf + 7 * M);        // 32768
  int*   OFFS = DEGI + 32768;               // 32769 (+1 pad)
  int*   CUR  = OFFS + 32770;               // 32768
  float* DIS  = (float*)(CUR + 32768);      // 32768
  int2*  EREC = (int2*)(DIS + 32768);       // E records (8B each), 8B-aligned
  float* W2T  = (float*)(EREC + E);         // 65536 floats (pre-transposed ff2_w)
  // buffer reuse for GCN stage
  float* G   = QT;   // free after attn
  float* XW  = KT;   // free after attn
  float* AGG = VT;   // free after attn
  float* XW2 = O;    // free after proj_ln1
  float* AG2 = Z;    // free after proj_ln1

  w2t_kernel<<<64, 256, 0, stream>>>(ff2_w, W2T);
  conv_kernel<<<1024, 256, 0, stream>>>(x, conv_w, conv_b, Z);
  qkv_kernel<<<128, 256, 0, stream>>>(Z, in_w, in_b, QT, KT, VT);
  attn_kernel<<<512, 256, 0, stream>>>(QT, KT, VT, O);
  proj_ln1_kernel<<<128, 256, 0, stream>>>(Z, O, out_w, out_b, ln1_w, ln1_b, ZN1);
  ffn_kernel<<<256, 256, 0, stream>>>(ZN1, ff1_w, ff1_b, W2T, ff2_b, ln2_w, ln2_b, ZN2);
  transpose_kernel<<<1024, 256, 0, stream>>>(ZN2, G);
  // CSR build (independent of features; uses only edge_index)
  hipMemsetAsync(DEGI, 0, 32768 * sizeof(int), stream);
  degi_kernel<<<(E + 255) / 256, 256, 0, stream>>>(colp, DEGI, E);
  scan_kernel<<<1, 1024, 0, stream>>>(DEGI, OFFS, CUR, DIS, E);
  fill_kernel<<<(E + 255) / 256, 256, 0, stream>>>(rowp, colp, DIS, CUR, EREC, E);
  // GCN layer 1
  gcn_in_kernel<<<128, 256, 0, stream>>>(G, gcn_w, XW);
  gather_kernel<<<1024, 256, 0, stream>>>(XW, DIS, OFFS, EREC, AGG);
  // GCN layer 2
  gcn_mid_kernel<<<128, 256, 0, stream>>>(AGG, gcn_b, gcn_w, XW2);
  gather_kernel<<<1024, 256, 0, stream>>>(XW2, DIS, OFFS, EREC, AG2);
  gcn_out_kernel<<<128, 256, 0, stream>>>(AG2, gcn_b, fc_w, fc_b, (float*)d_out);
}

// Round 9
// 736.741 us; speedup vs baseline: 1.2536x; 1.2536x over previous
//
#include <hip/hip_runtime.h>

#define NTOK 32768

// ---------------- conv 3x3 SAME + bias -> z[token][32] ----------------
__global__ __launch_bounds__(256) void conv_kernel(
    const float* __restrict__ x, const float* __restrict__ w,
    const float* __restrict__ bias, float* __restrict__ z) {
  __shared__ float xs[16 * 32];     // [ci][y*8+x]
  __shared__ float wsm[32 * 145];   // [co][ci*9+t], padded stride 145
  __shared__ float bs[32];
  int b = blockIdx.x, tid = threadIdx.x;
  const float* xb = x + b * 512;
  for (int i = tid; i < 512; i += 256) xs[i] = xb[i];
  for (int i = tid; i < 4608; i += 256) wsm[(i / 144) * 145 + (i % 144)] = w[i];
  if (tid < 32) bs[tid] = bias[tid];
  __syncthreads();
  #pragma unroll
  for (int r = 0; r < 4; ++r) {
    int oid = r * 256 + tid;
    int co = oid & 31, pos = oid >> 5;
    int y = pos >> 3, xx = pos & 7;
    float acc = bs[co];
    const float* wr = &wsm[co * 145];
    for (int ci = 0; ci < 16; ++ci) {
      #pragma unroll
      for (int ky = 0; ky < 3; ++ky) {
        int yy = y + ky - 1;
        if (yy < 0 || yy > 3) continue;
        #pragma unroll
        for (int kx = 0; kx < 3; ++kx) {
          int xc = xx + kx - 1;
          if (xc < 0 || xc > 7) continue;
          acc += xs[ci * 32 + yy * 8 + xc] * wr[ci * 9 + ky * 3 + kx];
        }
      }
    }
    z[(b * 32 + pos) * 32 + co] = acc;
  }
}

// ---------------- qkv projection -> transposed slabs [pos*4+h][b][8] ----------------
__global__ __launch_bounds__(256) void qkv_kernel(
    const float* __restrict__ z, const float* __restrict__ W,
    const float* __restrict__ bias, float* __restrict__ qt,
    float* __restrict__ kt, float* __restrict__ vt) {
  __shared__ float wsm[96 * 32];
  __shared__ float bs[96];
  int tid = threadIdx.x;
  for (int i = tid; i < 3072; i += 256) wsm[i] = W[i];
  if (tid < 96) bs[tid] = bias[tid];
  __syncthreads();
  int s = tid >> 3, bl = tid & 7;
  int b = blockIdx.x * 8 + bl;
  int token = b * 32 + s;
  float zr[32];
  const float4* zp = (const float4*)(z + token * 32);
  #pragma unroll
  for (int i = 0; i < 8; ++i) {
    float4 v = zp[i];
    zr[i * 4 + 0] = v.x; zr[i * 4 + 1] = v.y; zr[i * 4 + 2] = v.z; zr[i * 4 + 3] = v.w;
  }
  for (int part = 0; part < 3; ++part) {
    float* dst = part == 0 ? qt : (part == 1 ? kt : vt);
    for (int hh = 0; hh < 4; ++hh) {
      float out[8];
      #pragma unroll
      for (int j = 0; j < 8; ++j) {
        int jj = part * 32 + hh * 8 + j;
        float a = bs[jj];
        const float* wr = &wsm[jj * 32];
        #pragma unroll
        for (int k = 0; k < 32; ++k) a += zr[k] * wr[k];
        out[j] = a;
      }
      float4* p = (float4*)(dst + ((size_t)(s * 4 + hh) * 1024 + b) * 8);
      p[0] = make_float4(out[0], out[1], out[2], out[3]);
      p[1] = make_float4(out[4], out[5], out[6], out[7]);
    }
  }
}

// ---------------- attention v2: 2 queries/thread, one-pass softmax ----------------
// LDS-issue-bound analysis: K/V ds_read_b128 pair per iter is the cost; sharing it
// across 2 queries halves per-CU LDS instructions. grid 256 = 1 block/CU.
__global__ __launch_bounds__(256) void attn_kernel(
    const float* __restrict__ qt, const float* __restrict__ kt,
    const float* __restrict__ vt, float* __restrict__ o) {
  __shared__ __align__(16) float Ks[1024 * 8];
  __shared__ __align__(16) float Vs[1024 * 8];
  int slab = blockIdx.x >> 1, qh = blockIdx.x & 1;
  int tid = threadIdx.x;
  const float4* kp = (const float4*)(kt + (size_t)slab * 8192);
  const float4* vp = (const float4*)(vt + (size_t)slab * 8192);
  float4* ksp = (float4*)Ks;
  float4* vsp = (float4*)Vs;
  for (int i = tid; i < 2048; i += 256) { ksp[i] = kp[i]; vsp[i] = vp[i]; }
  __syncthreads();
  int b0 = qh * 512 + tid;   // query 0
  int b1 = b0 + 256;         // query 1
  const float scale = 0.35355339059327373f;
  const float4* qpa = (const float4*)(qt + ((size_t)slab * 1024 + b0) * 8);
  const float4* qpb = (const float4*)(qt + ((size_t)slab * 1024 + b1) * 8);
  float4 qa0 = qpa[0], qa1 = qpa[1], qb0 = qpb[0], qb1 = qpb[1];
  qa0.x *= scale; qa0.y *= scale; qa0.z *= scale; qa0.w *= scale;
  qa1.x *= scale; qa1.y *= scale; qa1.z *= scale; qa1.w *= scale;
  qb0.x *= scale; qb0.y *= scale; qb0.z *= scale; qb0.w *= scale;
  qb1.x *= scale; qb1.y *= scale; qb1.z *= scale; qb1.w *= scale;
  float la = 0.f, lb = 0.f;
  float aA[8] = {0, 0, 0, 0, 0, 0, 0, 0};
  float aB[8] = {0, 0, 0, 0, 0, 0, 0, 0};
  #pragma unroll 2
  for (int t = 0; t < 1024; ++t) {
    const float4* kk = (const float4*)&Ks[t * 8];
    float4 k0 = kk[0], k1 = kk[1];
    float sa = qa0.x * k0.x + qa0.y * k0.y + qa0.z * k0.z + qa0.w * k0.w +
               qa1.x * k1.x + qa1.y * k1.y + qa1.z * k1.z + qa1.w * k1.w;
    float sb = qb0.x * k0.x + qb0.y * k0.y + qb0.z * k0.z + qb0.w * k0.w +
               qb1.x * k1.x + qb1.y * k1.y + qb1.z * k1.z + qb1.w * k1.w;
    float pa = __expf(sa);
    float pb = __expf(sb);
    la += pa; lb += pb;
    const float4* vv = (const float4*)&Vs[t * 8];
    float4 v0 = vv[0], v1 = vv[1];
    aA[0] += pa * v0.x; aA[1] += pa * v0.y; aA[2] += pa * v0.z; aA[3] += pa * v0.w;
    aA[4] += pa * v1.x; aA[5] += pa * v1.y; aA[6] += pa * v1.z; aA[7] += pa * v1.w;
    aB[0] += pb * v0.x; aB[1] += pb * v0.y; aB[2] += pb * v0.z; aB[3] += pb * v0.w;
    aB[4] += pb * v1.x; aB[5] += pb * v1.y; aB[6] += pb * v1.z; aB[7] += pb * v1.w;
  }
  int npos = slab >> 2, hh = slab & 3;
  float inv = 1.f / la;
  float4* op = (float4*)(o + ((size_t)(b0 * 32 + npos)) * 32 + hh * 8);
  op[0] = make_float4(aA[0] * inv, aA[1] * inv, aA[2] * inv, aA[3] * inv);
  op[1] = make_float4(aA[4] * inv, aA[5] * inv, aA[6] * inv, aA[7] * inv);
  inv = 1.f / lb;
  op = (float4*)(o + ((size_t)(b1 * 32 + npos)) * 32 + hh * 8);
  op[0] = make_float4(aB[0] * inv, aB[1] * inv, aB[2] * inv, aB[3] * inv);
  op[1] = make_float4(aB[4] * inv, aB[5] * inv, aB[6] * inv, aB[7] * inv);
}

// ---------------- out-proj + residual + LN1 ----------------
__global__ __launch_bounds__(256) void proj_ln1_kernel(
    const float* __restrict__ z, const float* __restrict__ o,
    const float* __restrict__ W, const float* __restrict__ bias,
    const float* __restrict__ lw, const float* __restrict__ lb,
    float* __restrict__ zn1) {
  __shared__ float wsm[1024];
  __shared__ float bs[32], lws[32], lbs[32];
  int tid = threadIdx.x;
  for (int i = tid; i < 1024; i += 256) wsm[i] = W[i];
  if (tid < 32) { bs[tid] = bias[tid]; lws[tid] = lw[tid]; lbs[tid] = lb[tid]; }
  __syncthreads();
  int token = blockIdx.x * 256 + tid;
  float orow[32], zrow[32], v[32];
  const float4* opnt = (const float4*)(o + (size_t)token * 32);
  const float4* zp = (const float4*)(z + (size_t)token * 32);
  #pragma unroll
  for (int i = 0; i < 8; ++i) {
    float4 t4 = opnt[i];
    orow[i * 4] = t4.x; orow[i * 4 + 1] = t4.y; orow[i * 4 + 2] = t4.z; orow[i * 4 + 3] = t4.w;
    float4 z4 = zp[i];
    zrow[i * 4] = z4.x; zrow[i * 4 + 1] = z4.y; zrow[i * 4 + 2] = z4.z; zrow[i * 4 + 3] = z4.w;
  }
  float s1 = 0.f, s2 = 0.f;
  for (int j = 0; j < 32; ++j) {
    float a = bs[j];
    const float* wr = &wsm[j * 32];
    #pragma unroll
    for (int k = 0; k < 32; ++k) a += orow[k] * wr[k];
    float t = a + zrow[j];
    v[j] = t; s1 += t; s2 += t * t;
  }
  float mean = s1 * (1.f / 32.f);
  float var = s2 * (1.f / 32.f) - mean * mean;
  float rs = rsqrtf(var + 1e-5f);
  float4* dst = (float4*)(zn1 + (size_t)token * 32);
  #pragma unroll
  for (int k4 = 0; k4 < 8; ++k4) {
    float4 ov;
    ov.x = (v[k4 * 4 + 0] - mean) * rs * lws[k4 * 4 + 0] + lbs[k4 * 4 + 0];
    ov.y = (v[k4 * 4 + 1] - mean) * rs * lws[k4 * 4 + 1] + lbs[k4 * 4 + 1];
    ov.z = (v[k4 * 4 + 2] - mean) * rs * lws[k4 * 4 + 2] + lbs[k4 * 4 + 2];
    ov.w = (v[k4 * 4 + 3] - mean) * rs * lws[k4 * 4 + 3] + lbs[k4 * 4 + 3];
    dst[k4] = ov;
  }
}

// ---------------- fused FFN (R5 version, best measured 218us): T=2, 8-lane f-split ----------------
__global__ __launch_bounds__(256, 2) void ffn_kernel(
    const float* __restrict__ zn1, const float* __restrict__ w1,
    const float* __restrict__ b1, const float* __restrict__ w2,
    const float* __restrict__ b2, const float* __restrict__ lw,
    const float* __restrict__ lb, float* __restrict__ zn2) {
  __shared__ __align__(16) float w1s[128 * 36];
  __shared__ __align__(16) float w2s[128 * 36];
  __shared__ float b1s[128];
  __shared__ float lws[32], lbs[32], b2s[32];
  int tid = threadIdx.x;
  int p = tid >> 3, fg = tid & 7;
  int t0 = blockIdx.x * 64 + p * 2;
  float z0[32], z1[32], acc0[32], acc1[32];
  const float4* zp0 = (const float4*)(zn1 + (size_t)t0 * 32);
  const float4* zp1 = (const float4*)(zn1 + (size_t)(t0 + 1) * 32);
  #pragma unroll
  for (int i = 0; i < 8; ++i) {
    float4 a = zp0[i];
    z0[i * 4 + 0] = a.x; z0[i * 4 + 1] = a.y; z0[i * 4 + 2] = a.z; z0[i * 4 + 3] = a.w;
    float4 b = zp1[i];
    z1[i * 4 + 0] = b.x; z1[i * 4 + 1] = b.y; z1[i * 4 + 2] = b.z; z1[i * 4 + 3] = b.w;
  }
  #pragma unroll
  for (int d = 0; d < 32; ++d) { acc0[d] = 0.f; acc1[d] = 0.f; }
  if (tid < 32) { lws[tid] = lw[tid]; lbs[tid] = lb[tid]; b2s[tid] = b2[tid]; }
  for (int ch = 0; ch < 16; ++ch) {
    __syncthreads();
    // stage w1 chunk: w1s[fr][k] from w1[(ch*128+fr)*32+k] (coalesced b128)
    #pragma unroll
    for (int pass = 0; pass < 4; ++pass) {
      int idx = pass * 256 + tid;
      int fr = idx >> 3, k4 = idx & 7;
      float4 v = ((const float4*)(w1 + (size_t)(ch * 128 + fr) * 32))[k4];
      float* dptr = &w1s[fr * 36 + k4 * 4];
      dptr[0] = v.x; dptr[1] = v.y; dptr[2] = v.z; dptr[3] = v.w;
    }
    // stage w2 chunk transposed: w2s[f][d] from w2[d*2048 + ch*128 + f] (coalesced b128)
    #pragma unroll
    for (int pass = 0; pass < 4; ++pass) {
      int idx = pass * 256 + tid;
      int dd = idx >> 5, f4 = idx & 31;
      float4 v = ((const float4*)(w2 + (size_t)dd * 2048 + ch * 128))[f4];
      w2s[(f4 * 4 + 0) * 36 + dd] = v.x;
      w2s[(f4 * 4 + 1) * 36 + dd] = v.y;
      w2s[(f4 * 4 + 2) * 36 + dd] = v.z;
      w2s[(f4 * 4 + 3) * 36 + dd] = v.w;
    }
    if (tid < 128) b1s[tid] = b1[ch * 128 + tid];
    __syncthreads();
    #pragma unroll 4
    for (int i = 0; i < 16; ++i) {
      int f = i * 8 + fg;
      const float4* wr = (const float4*)&w1s[f * 36];
      float h0 = b1s[f], h1 = h0;
      #pragma unroll
      for (int k4 = 0; k4 < 8; ++k4) {
        float4 wv = wr[k4];
        h0 += z0[k4 * 4 + 0] * wv.x + z0[k4 * 4 + 1] * wv.y + z0[k4 * 4 + 2] * wv.z + z0[k4 * 4 + 3] * wv.w;
        h1 += z1[k4 * 4 + 0] * wv.x + z1[k4 * 4 + 1] * wv.y + z1[k4 * 4 + 2] * wv.z + z1[k4 * 4 + 3] * wv.w;
      }
      h0 = fmaxf(h0, 0.f); h1 = fmaxf(h1, 0.f);
      const float4* vr = (const float4*)&w2s[f * 36];
      #pragma unroll
      for (int d4 = 0; d4 < 8; ++d4) {
        float4 vv = vr[d4];
        acc0[d4 * 4 + 0] += h0 * vv.x; acc0[d4 * 4 + 1] += h0 * vv.y;
        acc0[d4 * 4 + 2] += h0 * vv.z; acc0[d4 * 4 + 3] += h0 * vv.w;
        acc1[d4 * 4 + 0] += h1 * vv.x; acc1[d4 * 4 + 1] += h1 * vv.y;
        acc1[d4 * 4 + 2] += h1 * vv.z; acc1[d4 * 4 + 3] += h1 * vv.w;
      }
    }
  }
  // reduce across the 8 fg lanes (adjacent in-wave)
  #pragma unroll
  for (int d = 0; d < 32; ++d) {
    float a = acc0[d];
    a += __shfl_xor(a, 1); a += __shfl_xor(a, 2); a += __shfl_xor(a, 4);
    acc0[d] = a;
    float b = acc1[d];
    b += __shfl_xor(b, 1); b += __shfl_xor(b, 2); b += __shfl_xor(b, 4);
    acc1[d] = b;
  }
  if (fg == 0) {
    float v[32];
    float s1 = 0.f, s2 = 0.f;
    #pragma unroll
    for (int d = 0; d < 32; ++d) {
      float t = z0[d] + acc0[d] + b2s[d];
      v[d] = t; s1 += t; s2 += t * t;
    }
    float mean = s1 * (1.f / 32.f);
    float var = s2 * (1.f / 32.f) - mean * mean;
    float rs = rsqrtf(var + 1e-5f);
    float4* dst = (float4*)(zn2 + (size_t)t0 * 32);
    #pragma unroll
    for (int k4 = 0; k4 < 8; ++k4) {
      float4 ov;
      ov.x = (v[k4 * 4 + 0] - mean) * rs * lws[k4 * 4 + 0] + lbs[k4 * 4 + 0];
      ov.y = (v[k4 * 4 + 1] - mean) * rs * lws[k4 * 4 + 1] + lbs[k4 * 4 + 1];
      ov.z = (v[k4 * 4 + 2] - mean) * rs * lws[k4 * 4 + 2] + lbs[k4 * 4 + 2];
      ov.w = (v[k4 * 4 + 3] - mean) * rs * lws[k4 * 4 + 3] + lbs[k4 * 4 + 3];
      dst[k4] = ov;
    }
    float s1b = 0.f, s2b = 0.f;
    #pragma unroll
    for (int d = 0; d < 32; ++d) {
      float t = z1[d] + acc1[d] + b2s[d];
      v[d] = t; s1b += t; s2b += t * t;
    }
    mean = s1b * (1.f / 32.f);
    var = s2b * (1.f / 32.f) - mean * mean;
    rs = rsqrtf(var + 1e-5f);
    dst = (float4*)(zn2 + (size_t)(t0 + 1) * 32);
    #pragma unroll
    for (int k4 = 0; k4 < 8; ++k4) {
      float4 ov;
      ov.x = (v[k4 * 4 + 0] - mean) * rs * lws[k4 * 4 + 0] + lbs[k4 * 4 + 0];
      ov.y = (v[k4 * 4 + 1] - mean) * rs * lws[k4 * 4 + 1] + lbs[k4 * 4 + 1];
      ov.z = (v[k4 * 4 + 2] - mean) * rs * lws[k4 * 4 + 2] + lbs[k4 * 4 + 2];
      ov.w = (v[k4 * 4 + 3] - mean) * rs * lws[k4 * 4 + 3] + lbs[k4 * 4 + 3];
      dst[k4] = ov;
    }
  }
}

// ---------------- transpose per batch: g[b*32+c][s] = z2[b*32+s][c] ----------------
__global__ __launch_bounds__(256) void transpose_kernel(
    const float* __restrict__ zn2, float* __restrict__ g) {
  __shared__ float t[32 * 33];
  int b = blockIdx.x, tid = threadIdx.x;
  const float* src = zn2 + (size_t)b * 1024;
  #pragma unroll
  for (int l = 0; l < 4; ++l) {
    int o_ = l * 256 + tid;
    t[(o_ >> 5) * 33 + (o_ & 31)] = src[o_];
  }
  __syncthreads();
  float* dst = g + (size_t)b * 1024;
  #pragma unroll
  for (int l = 0; l < 4; ++l) {
    int o_ = l * 256 + tid;
    int c = o_ >> 5, s = o_ & 31;
    dst[o_] = t[s * 33 + c];
  }
}

// ---------------- CSR build: int degree histogram ----------------
__global__ void degi_kernel(const int* __restrict__ col, int* __restrict__ degi, int E) {
  int e = blockIdx.x * 256 + threadIdx.x;
  if (e < E) atomicAdd(&degi[col[e]], 1);
}

// ---------------- single-block scan: offs = exclusive prefix(degi); cur=offs; dis ----------------
__global__ __launch_bounds__(1024) void scan_kernel(
    const int* __restrict__ degi, int* __restrict__ offs, int* __restrict__ cur,
    float* __restrict__ dis, int E) {
  __shared__ int ts[1024];
  int tid = threadIdx.x;
  int base = tid * 32;
  int loc[32];
  int s = 0;
  #pragma unroll
  for (int i = 0; i < 32; ++i) { loc[i] = s; s += degi[base + i]; }
  ts[tid] = s;
  __syncthreads();
  for (int d = 1; d < 1024; d <<= 1) {
    int v = (tid >= d) ? ts[tid - d] : 0;
    __syncthreads();
    ts[tid] += v;
    __syncthreads();
  }
  int excl = (tid == 0) ? 0 : ts[tid - 1];
  #pragma unroll
  for (int i = 0; i < 32; ++i) {
    int o = excl + loc[i];
    offs[base + i] = o;
    cur[base + i] = o;
    dis[base + i] = rsqrtf((float)(degi[base + i] + 1));  // +1 self-loop
  }
  if (tid == 1023) offs[NTOK] = E;
}

// ---------------- CSR fill: erec[slot] = (row, dis[row]*dis[col]) ----------------
__global__ void fill_kernel(const int* __restrict__ row, const int* __restrict__ col,
                            const float* __restrict__ dis, int* __restrict__ cur,
                            int2* __restrict__ erec, int E) {
  int e = blockIdx.x * 256 + threadIdx.x;
  if (e >= E) return;
  int r = row[e], c = col[e];
  int slot = atomicAdd(&cur[c], 1);
  float nrm = dis[r] * dis[c];
  erec[slot] = make_int2(r, __float_as_int(nrm));
}

// ---------------- GCN xw = g@W^T (layer input transform) ----------------
__global__ __launch_bounds__(256) void gcn_in_kernel(
    const float* __restrict__ g, const float* __restrict__ w,
    float* __restrict__ xw) {
  __shared__ float wsm[1024];
  int tid = threadIdx.x;
  for (int i = tid; i < 1024; i += 256) wsm[i] = w[i];
  __syncthreads();
  int n = blockIdx.x * 256 + tid;
  float gr[32];
  const float4* gp = (const float4*)(g + (size_t)n * 32);
  #pragma unroll
  for (int i = 0; i < 8; ++i) {
    float4 v = gp[i];
    gr[i * 4] = v.x; gr[i * 4 + 1] = v.y; gr[i * 4 + 2] = v.z; gr[i * 4 + 3] = v.w;
  }
  float4* xp = (float4*)(xw + (size_t)n * 32);
  for (int d4 = 0; d4 < 8; ++d4) {
    float o_[4];
    #pragma unroll
    for (int j = 0; j < 4; ++j) {
      const float* wr = &wsm[(d4 * 4 + j) * 32];
      float a = 0.f;
      #pragma unroll
      for (int k = 0; k < 32; ++k) a += gr[k] * wr[k];
      o_[j] = a;
    }
    xp[d4] = make_float4(o_[0], o_[1], o_[2], o_[3]);
  }
}

// ---------------- GCN gather: agg[c] = xw[c]*dis[c]^2 + sum_e xw[row_e]*nrm_e ----------------
__global__ __launch_bounds__(256) void gather_kernel(
    const float* __restrict__ xw, const float* __restrict__ dis,
    const int* __restrict__ offs, const int2* __restrict__ erec,
    float* __restrict__ agg) {
  int gid = blockIdx.x * 256 + threadIdx.x;
  int c = gid >> 3, q = gid & 7;
  int start = offs[c], end = offs[c + 1];
  float dn = dis[c];
  float dn2 = dn * dn;
  float4 self = ((const float4*)(xw + (size_t)c * 32))[q];
  float a0 = self.x * dn2, a1 = self.y * dn2, a2 = self.z * dn2, a3 = self.w * dn2;
  int e = start;
  #pragma unroll 4
  for (; e < end; ++e) {
    int2 rec = erec[e];
    float nrm = __int_as_float(rec.y);
    float4 v = ((const float4*)(xw + (size_t)rec.x * 32))[q];
    a0 += v.x * nrm; a1 += v.y * nrm; a2 += v.z * nrm; a3 += v.w * nrm;
  }
  ((float4*)(agg + (size_t)c * 32))[q] = make_float4(a0, a1, a2, a3);
}

// ---------------- GCN mid: g1 = relu(agg+b); xw2 = g1@W^T ----------------
__global__ __launch_bounds__(256) void gcn_mid_kernel(
    const float* __restrict__ agg, const float* __restrict__ gb,
    const float* __restrict__ w, float* __restrict__ xw2) {
  __shared__ float wsm[1024];
  __shared__ float bs[32];
  int tid = threadIdx.x;
  for (int i = tid; i < 1024; i += 256) wsm[i] = w[i];
  if (tid < 32) bs[tid] = gb[tid];
  __syncthreads();
  int n = blockIdx.x * 256 + tid;
  float gr[32];
  const float4* ap = (const float4*)(agg + (size_t)n * 32);
  #pragma unroll
  for (int i = 0; i < 8; ++i) {
    float4 v = ap[i];
    gr[i * 4 + 0] = fmaxf(v.x + bs[i * 4 + 0], 0.f);
    gr[i * 4 + 1] = fmaxf(v.y + bs[i * 4 + 1], 0.f);
    gr[i * 4 + 2] = fmaxf(v.z + bs[i * 4 + 2], 0.f);
    gr[i * 4 + 3] = fmaxf(v.w + bs[i * 4 + 3], 0.f);
  }
  float4* xp = (float4*)(xw2 + (size_t)n * 32);
  for (int d4 = 0; d4 < 8; ++d4) {
    float o_[4];
    #pragma unroll
    for (int j = 0; j < 4; ++j) {
      const float* wr = &wsm[(d4 * 4 + j) * 32];
      float a = 0.f;
      #pragma unroll
      for (int k = 0; k < 32; ++k) a += gr[k] * wr[k];
      o_[j] = a;
    }
    xp[d4] = make_float4(o_[0], o_[1], o_[2], o_[3]);
  }
}

// ---------------- final: fc + log_softmax ----------------
__global__ __launch_bounds__(256) void gcn_out_kernel(
    const float* __restrict__ agg2, const float* __restrict__ gb,
    const float* __restrict__ fw, const float* __restrict__ fb,
    float* __restrict__ out) {
  __shared__ float wsm[320];
  __shared__ float bs[10];
  __shared__ float gbs[32];
  int tid = threadIdx.x;
  for (int i = tid; i < 320; i += 256) wsm[i] = fw[i];
  if (tid < 10) bs[tid] = fb[tid];
  if (tid < 32) gbs[tid] = gb[tid];
  __syncthreads();
  int n = blockIdx.x * 256 + tid;
  float v[32];
  const float4* ap = (const float4*)(agg2 + (size_t)n * 32);
  #pragma unroll
  for (int i = 0; i < 8; ++i) {
    float4 t4 = ap[i];
    v[i * 4 + 0] = t4.x + gbs[i * 4 + 0];
    v[i * 4 + 1] = t4.y + gbs[i * 4 + 1];
    v[i * 4 + 2] = t4.z + gbs[i * 4 + 2];
    v[i * 4 + 3] = t4.w + gbs[i * 4 + 3];
  }
  float lg[10];
  float mx = -1e30f;
  for (int j = 0; j < 10; ++j) {
    float a = bs[j];
    const float* wr = &wsm[j * 32];
    #pragma unroll
    for (int k = 0; k < 32; ++k) a += v[k] * wr[k];
    lg[j] = a;
    mx = fmaxf(mx, a);
  }
  float se = 0.f;
  for (int j = 0; j < 10; ++j) se += __expf(lg[j] - mx);
  float ls = logf(se);
  for (int j = 0; j < 10; ++j) out[(size_t)n * 10 + j] = lg[j] - mx - ls;
}

extern "C" void kernel_launch(void* const* d_in, const int* in_sizes, int n_in,
                              void* d_out, int out_size, void* d_ws, size_t ws_size,
                              hipStream_t stream) {
  const float* x      = (const float*)d_in[0];
  const int*   ei     = (const int*)d_in[1];
  const float* conv_w = (const float*)d_in[2];
  const float* conv_b = (const float*)d_in[3];
  const float* in_w   = (const float*)d_in[4];
  const float* in_b   = (const float*)d_in[5];
  const float* out_w  = (const float*)d_in[6];
  const float* out_b  = (const float*)d_in[7];
  const float* ln1_w  = (const float*)d_in[8];
  const float* ln1_b  = (const float*)d_in[9];
  const float* ln2_w  = (const float*)d_in[10];
  const float* ln2_b  = (const float*)d_in[11];
  const float* ff1_w  = (const float*)d_in[12];
  const float* ff1_b  = (const float*)d_in[13];
  const float* ff2_w  = (const float*)d_in[14];
  const float* ff2_b  = (const float*)d_in[15];
  const float* gcn_w  = (const float*)d_in[16];
  const float* gcn_b  = (const float*)d_in[17];
  const float* fc_w   = (const float*)d_in[18];
  const float* fc_b   = (const float*)d_in[19];
  int E = in_sizes[1] / 2;
  const int* rowp = ei;
  const int* colp = ei + E;

  float* wsf = (float*)d_ws;
  const size_t M = 1048576;  // floats per 4 MB buffer
  float* Z   = wsf + 0 * M;
  float* QT  = wsf + 1 * M;
  float* KT  = wsf + 2 * M;
  float* VT  = wsf + 3 * M;
  float* O   = wsf + 4 * M;
  float* ZN1 = wsf + 5 * M;
  float* ZN2 = wsf + 6 * M;
  // CSR area after the 7 big buffers
  int*   DEGI = (int*)(wsf + 7 * M);        // 32768
  int*   OFFS = DEGI + 32768;               // 32769 (+1 pad)
  int*   CUR  = OFFS + 32770;               // 32768
  float* DIS  = (float*)(CUR + 32768);      // 32768
  int2*  EREC = (int2*)(DIS + 32768);       // E records (8B each), 8B-aligned
  // buffer reuse for GCN stage
  float* G   = QT;   // free after attn
  float* XW  = KT;   // free after attn
  float* AGG = VT;   // free after attn
  float* XW2 = O;    // free after proj_ln1
  float* AG2 = Z;    // free after proj_ln1

  conv_kernel<<<1024, 256, 0, stream>>>(x, conv_w, conv_b, Z);
  qkv_kernel<<<128, 256, 0, stream>>>(Z, in_w, in_b, QT, KT, VT);
  attn_kernel<<<256, 256, 0, stream>>>(QT, KT, VT, O);
  proj_ln1_kernel<<<128, 256, 0, stream>>>(Z, O, out_w, out_b, ln1_w, ln1_b, ZN1);
  ffn_kernel<<<512, 256, 0, stream>>>(ZN1, ff1_w, ff1_b, ff2_w, ff2_b, ln2_w, ln2_b, ZN2);
  transpose_kernel<<<1024, 256, 0, stream>>>(ZN2, G);
  // CSR build (independent of features; uses only edge_index)
  hipMemsetAsync(DEGI, 0, 32768 * sizeof(int), stream);
  degi_kernel<<<(E + 255) / 256, 256, 0, stream>>>(colp, DEGI, E);
  scan_kernel<<<1, 1024, 0, stream>>>(DEGI, OFFS, CUR, DIS, E);
  fill_kernel<<<(E + 255) / 256, 256, 0, stream>>>(rowp, colp, DIS, CUR, EREC, E);
  // GCN layer 1
  gcn_in_kernel<<<128, 256, 0, stream>>>(G, gcn_w, XW);
  gather_kernel<<<1024, 256, 0, stream>>>(XW, DIS, OFFS, EREC, AGG);
  // GCN layer 2
  gcn_mid_kernel<<<128, 256, 0, stream>>>(AGG, gcn_b, gcn_w, XW2);
  gather_kernel<<<1024, 256, 0, stream>>>(XW2, DIS, OFFS, EREC, AG2);
  gcn_out_kernel<<<128, 256, 0, stream>>>(AG2, gcn_b, fc_w, fc_b, (float*)d_out);
}